// Round 2
// baseline (15647.461 us; speedup 1.0000x reference)
//
#include <hip/hip_runtime.h>
#include <cstdint>
#include <cstddef>

#define BB 32
#define TT 512
#define NSTEPS 129   // L+1
#define EE 1024
#define DD 1024
#define AAD 512      // A (attention dim)
#define VV 5000
#define SOS 4999
#define KW 201
#define NFILT 100

__device__ __forceinline__ float fsig(float x){
    return __fdividef(1.0f, 1.0f + __expf(-x));
}
__device__ __forceinline__ float ftanh(float x){
    float ax = fabsf(x);
    float e = __expf(-2.0f*ax);
    float r = __fdividef(1.0f - e, 1.0f + e);
    return copysignf(r, x);
}

// ---------------------------------------------------------------------------
// init: aw = mask/hlen ; zero c0,c1, z0-slot of x0, z1-slot of x1, dec region of g1
__global__ void k_init(const int* __restrict__ hlens, float* __restrict__ aw,
                       float* __restrict__ x0, float* __restrict__ x1,
                       float* __restrict__ g1, float* __restrict__ c0,
                       float* __restrict__ c1)
{
    int idx = blockIdx.x*256 + threadIdx.x;   // 128 blocks -> 32768 threads
    if (idx < BB*TT){
        int b = idx >> 9;
        int t = idx & 511;
        int hl = hlens[b];
        aw[idx] = (t < hl) ? __fdividef(1.0f, (float)hl) : 0.0f;
    }
    if (idx < BB*1024){
        int b = idx >> 10, d = idx & 1023;
        x0[b*3072 + 2048 + d] = 0.0f;   // z0 carry slot
        x1[b*2048 + 1024 + d] = 0.0f;   // z1 carry slot
        c0[idx] = 0.0f;
        c1[idx] = 0.0f;
    }
    if (idx < BB*AAD){
        int b = idx >> 9, a = idx & 511;
        g1[b*4608 + 4096 + a] = 0.0f;   // dec_proj region
    }
}

// ---------------------------------------------------------------------------
// generic fp32 NT GEMM: C[m][n] = sum_k A[m][k]*B[n][k] + bias[n]
// BM=128 BN=64 BK=16, 256 threads, 8x4 per thread
template<bool GUARD, bool REMAP>
__global__ __launch_bounds__(256) void k_gemm_nt(
    const float* __restrict__ Am, const float* __restrict__ Bm,
    const float* __restrict__ bias, float* __restrict__ Cm,
    int M, int N, int K)
{
    __shared__ float as[16][132];
    __shared__ float bs[16][68];
    const int tid = threadIdx.x;
    const int m0 = blockIdx.x * 128, n0 = blockIdx.y * 64;
    const int tm = tid & 15, tn = tid >> 4;
    float acc[8][4];
#pragma unroll
    for (int i = 0; i < 8; ++i)
#pragma unroll
        for (int j = 0; j < 4; ++j) acc[i][j] = 0.0f;

    for (int k0 = 0; k0 < K; k0 += 16){
#pragma unroll
        for (int i = 0; i < 2; ++i){
            int idx = tid + i*256;
            int r = idx >> 2, q = idx & 3;
            int row = m0 + r;
            float4 v = make_float4(0.f,0.f,0.f,0.f);
            if (!GUARD || row < M) v = *(const float4*)(Am + (size_t)row*K + k0 + q*4);
            as[q*4+0][r] = v.x; as[q*4+1][r] = v.y;
            as[q*4+2][r] = v.z; as[q*4+3][r] = v.w;
        }
        {
            int r = tid >> 2, q = tid & 3;
            int row = n0 + r;
            float4 v = make_float4(0.f,0.f,0.f,0.f);
            if (!GUARD || row < N) v = *(const float4*)(Bm + (size_t)row*K + k0 + q*4);
            bs[q*4+0][r] = v.x; bs[q*4+1][r] = v.y;
            bs[q*4+2][r] = v.z; bs[q*4+3][r] = v.w;
        }
        __syncthreads();
#pragma unroll
        for (int kk = 0; kk < 16; ++kk){
            float4 a0 = *(const float4*)&as[kk][tm*8];
            float4 a1 = *(const float4*)&as[kk][tm*8+4];
            float4 b0 = *(const float4*)&bs[kk][tn*4];
            float av[8] = {a0.x,a0.y,a0.z,a0.w,a1.x,a1.y,a1.z,a1.w};
            float bv[4] = {b0.x,b0.y,b0.z,b0.w};
#pragma unroll
            for (int i = 0; i < 8; ++i)
#pragma unroll
                for (int j = 0; j < 4; ++j) acc[i][j] += av[i]*bv[j];
        }
        __syncthreads();
    }
#pragma unroll
    for (int i = 0; i < 8; ++i){
        int m = m0 + tm*8 + i;
        if (GUARD && m >= M) continue;
#pragma unroll
        for (int j = 0; j < 4; ++j){
            int n = n0 + tn*4 + j;
            if (GUARD && n >= N) continue;
            float v = acc[i][j] + bias[n];
            size_t dst;
            if (REMAP){
                // m = l*32 + b  ->  out[b][l][n]
                dst = ((size_t)(m & 31) * NSTEPS + (size_t)(m >> 5)) * VV + (size_t)n;
            } else {
                dst = (size_t)m * (size_t)N + (size_t)n;
            }
            Cm[dst] = v;
        }
    }
}

// ---------------------------------------------------------------------------
// attention energy: e[b,t] = sum_a tanh(pre_enc + conv_proj + dec_proj)*gvec[a] + gvec_b
// grid (8, 32): 64 t per block, 256 threads
__global__ __launch_bounds__(256) void k_e(
    const float* __restrict__ pre_enc, const float* __restrict__ aw,
    const float* __restrict__ g1,           // dec_proj lives at [b*4608 + 4096 + a]
    const float* __restrict__ conv_w,       // [10*201]
    const float* __restrict__ att_att_W,    // [512*10]
    const float* __restrict__ gvec_W,       // [512]
    const float* __restrict__ gvec_b,       // [1]
    float* __restrict__ e_out)
{
    __shared__ float awin[264];
    __shared__ float convs[10][64];
    __shared__ float watt_s[512*12];        // per a: w[0..9], dec, gv
    const int tc = blockIdx.x, b = blockIdx.y;
    const int t0 = tc * 64;
    const int tid = threadIdx.x;

    for (int idx = tid; idx < 264; idx += 256){
        int t = t0 - NFILT + idx;
        awin[idx] = (t >= 0 && t < TT) ? aw[b*TT + t] : 0.0f;
    }
    for (int idx = tid; idx < 5120; idx += 256){
        int a = idx / 10, c = idx % 10;
        watt_s[a*12 + c] = att_att_W[idx];
    }
    for (int idx = tid; idx < 512; idx += 256){
        watt_s[idx*12 + 10] = g1[b*4608 + 4096 + idx];
        watt_s[idx*12 + 11] = gvec_W[idx];
    }
    __syncthreads();

    // conv phase: conv[c][tl] = sum_k awin[tl+k]*w[c][k]; c is wave-uniform
    for (int idx = tid; idx < 640; idx += 256){
        int c = idx >> 6, tl = idx & 63;
        const float* wc = conv_w + c*KW;
        float s = 0.0f;
#pragma unroll 4
        for (int k = 0; k < KW; ++k) s += awin[tl + k] * wc[k];
        convs[c][tl] = s;
    }
    __syncthreads();

    // energy phase: 4 threads per t, interleaved a = 4j+q to dodge LDS bank conflicts
    const int q = tid & 3, tl = tid >> 2;
    const int t = t0 + tl;
    float cv[10];
#pragma unroll
    for (int c = 0; c < 10; ++c) cv[c] = convs[c][tl];
    const float* pre_row = pre_enc + (size_t)(b*TT + t)*AAD;
    float acc = 0.0f;
#pragma unroll 4
    for (int j = 0; j < 128; ++j){
        int a = (j << 2) | q;
        const float* wr = &watt_s[a*12];
        float4 w0 = *(const float4*)wr;
        float4 w1 = *(const float4*)(wr+4);
        float4 w2 = *(const float4*)(wr+8);   // w8, w9, dec, gv
        float cp = cv[0]*w0.x + cv[1]*w0.y + cv[2]*w0.z + cv[3]*w0.w
                 + cv[4]*w1.x + cv[5]*w1.y + cv[6]*w1.z + cv[7]*w1.w
                 + cv[8]*w2.x + cv[9]*w2.y;
        float v = pre_row[a] + w2.z + cp;
        acc += ftanh(v) * w2.w;
    }
    acc += __shfl_xor(acc, 1);
    acc += __shfl_xor(acc, 2);
    if (q == 0) e_out[b*TT + t] = acc + gvec_b[0];
}

// ---------------------------------------------------------------------------
// masked softmax over T (SCALING=2) + att_c + stage x0 (ey slot + att_c slot)
// grid (8, 32): 128 E-cols per block; 256 threads (2 t-halves)
__global__ __launch_bounds__(256) void k_soft_attc(
    const float* __restrict__ e_in, const float* __restrict__ hs,
    const int* __restrict__ hlens, const int* __restrict__ ys_pad,
    const float* __restrict__ embed_W,
    float* __restrict__ aw, float* __restrict__ x0, int s)
{
    __shared__ float p_s[512];
    __shared__ float red[256];
    const int qc = blockIdx.x, b = blockIdx.y;
    const int tid = threadIdx.x;
    const int hl = hlens[b];

    float e0 = e_in[b*TT + tid];
    float e1 = e_in[b*TT + 256 + tid];
    float v0 = 2.0f * e0;                       // tid < 256 <= hl always valid
    float v1 = (256 + tid < hl) ? 2.0f*e1 : -1e30f;
    float m = fmaxf(v0, v1);
#pragma unroll
    for (int ofs = 1; ofs < 64; ofs <<= 1) m = fmaxf(m, __shfl_xor(m, ofs));
    if ((tid & 63) == 0) red[tid >> 6] = m;
    __syncthreads();
    m = fmaxf(fmaxf(red[0], red[1]), fmaxf(red[2], red[3]));
    __syncthreads();

    float p0 = __expf(v0 - m);
    float p1 = (256 + tid < hl) ? __expf(v1 - m) : 0.0f;
    float sum = p0 + p1;
#pragma unroll
    for (int ofs = 1; ofs < 64; ofs <<= 1) sum += __shfl_xor(sum, ofs);
    if ((tid & 63) == 0) red[tid >> 6] = sum;
    __syncthreads();
    sum = red[0] + red[1] + red[2] + red[3];
    float rinv = 1.0f / sum;
    p_s[tid] = p0 * rinv;
    p_s[tid + 256] = p1 * rinv;
    if (qc == 0){
        aw[b*TT + tid] = p0 * rinv;
        aw[b*TT + 256 + tid] = p1 * rinv;
    }
    __syncthreads();

    // att_c over this block's 128 E-columns, split t into two halves
    const int i = tid & 127, th = tid >> 7;
    const int ec = qc*128 + i;
    const float* hrow = hs + (size_t)(b*TT + th*256)*EE + ec;
    float acc = 0.0f;
#pragma unroll 8
    for (int t = 0; t < 256; ++t) acc += p_s[th*256 + t] * hrow[(size_t)t*EE];
    red[tid] = acc;
    __syncthreads();
    if (th == 0){
        float attc = red[i] + red[128 + i];
        x0[b*3072 + 1024 + ec] = attc;                    // att_c slot
        int tok = (s == 0) ? SOS : ys_pad[b*128 + (s-1)];
        x0[b*3072 + qc*128 + tid] = embed_W[(size_t)tok*DD + qc*128 + tid];  // ey slot
    }
}

// ---------------------------------------------------------------------------
// batch-32 GEMM, wave computes 8b x 8n with lanes splitting K; butterfly reduce.
// gates0[b,n] = sum_{k<2048} x0[b,k]*w_ih0[n,k] + sum_{k<1024} x0[b,2048+k]*w_hh0[n,k]
__global__ __launch_bounds__(256) void k_gates0(
    const float* __restrict__ x0, const float* __restrict__ w_ih0,
    const float* __restrict__ w_hh0, float* __restrict__ g0)
{
    const int tid = threadIdx.x;
    const int lane = tid & 63;
    const int b0 = (tid >> 6) * 8;
    const int n0 = blockIdx.x * 8;
    float acc[8][8];
#pragma unroll
    for (int i = 0; i < 8; ++i)
#pragma unroll
        for (int j = 0; j < 8; ++j) acc[i][j] = 0.0f;

    const float* xbase = x0 + (size_t)b0*3072;
    {
        const float* wbase = w_ih0 + (size_t)n0*2048;
        for (int kc = 0; kc < 8; ++kc){
            int kb = kc*256 + lane*4;
            float4 xv[8], wv[8];
#pragma unroll
            for (int i = 0; i < 8; ++i) xv[i] = *(const float4*)&xbase[i*3072 + kb];
#pragma unroll
            for (int j = 0; j < 8; ++j) wv[j] = *(const float4*)&wbase[j*2048 + kb];
#pragma unroll
            for (int i = 0; i < 8; ++i)
#pragma unroll
                for (int j = 0; j < 8; ++j)
                    acc[i][j] += xv[i].x*wv[j].x + xv[i].y*wv[j].y
                               + xv[i].z*wv[j].z + xv[i].w*wv[j].w;
        }
    }
    {
        const float* wbase = w_hh0 + (size_t)n0*1024;
        for (int kc = 0; kc < 4; ++kc){
            int kb = kc*256 + lane*4;
            float4 xv[8], wv[8];
#pragma unroll
            for (int i = 0; i < 8; ++i) xv[i] = *(const float4*)&xbase[i*3072 + 2048 + kb];
#pragma unroll
            for (int j = 0; j < 8; ++j) wv[j] = *(const float4*)&wbase[j*1024 + kb];
#pragma unroll
            for (int i = 0; i < 8; ++i)
#pragma unroll
                for (int j = 0; j < 8; ++j)
                    acc[i][j] += xv[i].x*wv[j].x + xv[i].y*wv[j].y
                               + xv[i].z*wv[j].z + xv[i].w*wv[j].w;
        }
    }
    // cross-lane reduce of 64 components; result: lane l holds component bitrev6(l)
    float cur[64];
#pragma unroll
    for (int i = 0; i < 8; ++i)
#pragma unroll
        for (int j = 0; j < 8; ++j) cur[i*8+j] = acc[i][j];
#pragma unroll
    for (int rb = 0; rb < 6; ++rb){
        const int bit = 1 << rb;
        const int half = 32 >> rb;
        const bool up = (lane & bit) != 0;
#pragma unroll
        for (int i = 0; i < half; ++i){
            float lo = cur[i], hi = cur[i + half];
            float send = up ? lo : hi;
            float keep = up ? hi : lo;
            cur[i] = keep + __shfl_xor(send, bit);
        }
    }
    int ci = (int)(__brev((unsigned)lane) >> 26);
    int ib = ci >> 3, jn = ci & 7;
    g0[(b0 + ib)*4096 + n0 + jn] = cur[0];
}

// gates1 (+ fused dec_proj rows 4096..4607):
// n<4096:   g1[b,n] = sum_k x1[b,k]*w_ih1[n,k] + sum_k x1[b,1024+k]*w_hh1[n,k]
// n>=4096:  g1[b,n] = sum_k x1[b,k]*att_dec_W[n-4096,k]
__global__ __launch_bounds__(256) void k_gates1(
    const float* __restrict__ x1, const float* __restrict__ w_ih1,
    const float* __restrict__ w_hh1, const float* __restrict__ dec_W,
    float* __restrict__ g1)
{
    const int tid = threadIdx.x;
    const int lane = tid & 63;
    const int b0 = (tid >> 6) * 8;
    const int n0 = blockIdx.x * 8;
    const bool isdec = (n0 >= 4096);
    float acc[8][8];
#pragma unroll
    for (int i = 0; i < 8; ++i)
#pragma unroll
        for (int j = 0; j < 8; ++j) acc[i][j] = 0.0f;

    const float* xbase = x1 + (size_t)b0*2048;
    {
        const float* wbase = isdec ? dec_W + (size_t)(n0-4096)*1024
                                   : w_ih1 + (size_t)n0*1024;
        for (int kc = 0; kc < 4; ++kc){
            int kb = kc*256 + lane*4;
            float4 xv[8], wv[8];
#pragma unroll
            for (int i = 0; i < 8; ++i) xv[i] = *(const float4*)&xbase[i*2048 + kb];
#pragma unroll
            for (int j = 0; j < 8; ++j) wv[j] = *(const float4*)&wbase[j*1024 + kb];
#pragma unroll
            for (int i = 0; i < 8; ++i)
#pragma unroll
                for (int j = 0; j < 8; ++j)
                    acc[i][j] += xv[i].x*wv[j].x + xv[i].y*wv[j].y
                               + xv[i].z*wv[j].z + xv[i].w*wv[j].w;
        }
    }
    if (!isdec){
        const float* wbase = w_hh1 + (size_t)n0*1024;
        for (int kc = 0; kc < 4; ++kc){
            int kb = kc*256 + lane*4;
            float4 xv[8], wv[8];
#pragma unroll
            for (int i = 0; i < 8; ++i) xv[i] = *(const float4*)&xbase[i*2048 + 1024 + kb];
#pragma unroll
            for (int j = 0; j < 8; ++j) wv[j] = *(const float4*)&wbase[j*1024 + kb];
#pragma unroll
            for (int i = 0; i < 8; ++i)
#pragma unroll
                for (int j = 0; j < 8; ++j)
                    acc[i][j] += xv[i].x*wv[j].x + xv[i].y*wv[j].y
                               + xv[i].z*wv[j].z + xv[i].w*wv[j].w;
        }
    }
    float cur[64];
#pragma unroll
    for (int i = 0; i < 8; ++i)
#pragma unroll
        for (int j = 0; j < 8; ++j) cur[i*8+j] = acc[i][j];
#pragma unroll
    for (int rb = 0; rb < 6; ++rb){
        const int bit = 1 << rb;
        const int half = 32 >> rb;
        const bool up = (lane & bit) != 0;
#pragma unroll
        for (int i = 0; i < half; ++i){
            float lo = cur[i], hi = cur[i + half];
            float send = up ? lo : hi;
            float keep = up ? hi : lo;
            cur[i] = keep + __shfl_xor(send, bit);
        }
    }
    int ci = (int)(__brev((unsigned)lane) >> 26);
    int ib = ci >> 3, jn = ci & 7;
    g1[(b0 + ib)*4608 + n0 + jn] = cur[0];
}

// ---------------------------------------------------------------------------
__global__ void k_lstm0(const float* __restrict__ g0, const float* __restrict__ bi,
                        const float* __restrict__ bh, float* __restrict__ c0,
                        float* __restrict__ x0, float* __restrict__ x1)
{
    int idx = blockIdx.x*256 + threadIdx.x;   // 32768
    int b = idx >> 10, d = idx & 1023;
    const float* gr = g0 + b*4096;
    float gi = gr[d]        + bi[d]        + bh[d];
    float gf = gr[1024 + d] + bi[1024 + d] + bh[1024 + d];
    float gg = gr[2048 + d] + bi[2048 + d] + bh[2048 + d];
    float go = gr[3072 + d] + bi[3072 + d] + bh[3072 + d];
    float c = fsig(gf)*c0[idx] + fsig(gi)*ftanh(gg);
    float h = fsig(go)*ftanh(c);
    c0[idx] = c;
    x0[b*3072 + 2048 + d] = h;   // z0 carry for next step's gates0
    x1[b*2048 + d] = h;          // z0 input for this step's gates1 (+dec next step)
}

__global__ void k_lstm1(const float* __restrict__ g1, const float* __restrict__ bi,
                        const float* __restrict__ bh, float* __restrict__ c1,
                        float* __restrict__ x1, float* __restrict__ zs, int s)
{
    int idx = blockIdx.x*256 + threadIdx.x;   // 32768
    int b = idx >> 10, d = idx & 1023;
    const float* gr = g1 + b*4608;
    float gi = gr[d]        + bi[d]        + bh[d];
    float gf = gr[1024 + d] + bi[1024 + d] + bh[1024 + d];
    float gg = gr[2048 + d] + bi[2048 + d] + bh[2048 + d];
    float go = gr[3072 + d] + bi[3072 + d] + bh[3072 + d];
    float c = fsig(gf)*c1[idx] + fsig(gi)*ftanh(gg);
    float h = fsig(go)*ftanh(c);
    c1[idx] = c;
    x1[b*2048 + 1024 + d] = h;                   // z1 carry for next step's gates1
    zs[(size_t)(s*32 + b)*1024 + d] = h;         // scan output
}

// ---------------------------------------------------------------------------
extern "C" void kernel_launch(void* const* d_in, const int* in_sizes, int n_in,
                              void* d_out, int out_size, void* d_ws, size_t ws_size,
                              hipStream_t stream)
{
    const float* hs      = (const float*)d_in[0];
    const int*   hlens   = (const int*)d_in[1];
    const int*   ys_pad  = (const int*)d_in[2];
    const float* embed_W = (const float*)d_in[3];
    const float* w_ih0   = (const float*)d_in[4];
    const float* w_hh0   = (const float*)d_in[5];
    const float* b_ih0   = (const float*)d_in[6];
    const float* b_hh0   = (const float*)d_in[7];
    const float* w_ih1   = (const float*)d_in[8];
    const float* w_hh1   = (const float*)d_in[9];
    const float* b_ih1   = (const float*)d_in[10];
    const float* b_hh1   = (const float*)d_in[11];
    const float* enc_W   = (const float*)d_in[12];
    const float* enc_b   = (const float*)d_in[13];
    const float* dec_W   = (const float*)d_in[14];
    const float* conv_W  = (const float*)d_in[15];
    const float* att_W   = (const float*)d_in[16];
    const float* gvec_W  = (const float*)d_in[17];
    const float* gvec_b  = (const float*)d_in[18];
    const float* out_W   = (const float*)d_in[19];
    const float* out_b   = (const float*)d_in[20];
    float* out = (float*)d_out;

    float* ws      = (float*)d_ws;
    float* pre_enc = ws;                    // [16384][512]
    float* aw      = pre_enc + 8388608;     // [32][512]
    float* e_buf   = aw + 16384;            // [32][512]
    float* x0      = e_buf + 16384;         // [32][3072]  ey | att_c | z0
    float* x1      = x0 + 98304;            // [32][2048]  z0 | z1
    float* g0      = x1 + 65536;            // [32][4096]
    float* g1      = g0 + 131072;           // [32][4608]  gates | dec_proj
    float* c0      = g1 + 147456;           // [32][1024]
    float* c1      = c0 + 32768;            // [32][1024]
    float* zs      = c1 + 32768;            // [129][32][1024]

    k_init<<<128, 256, 0, stream>>>(hlens, aw, x0, x1, g1, c0, c1);
    k_gemm_nt<false,false><<<dim3(128, 8), 256, 0, stream>>>(
        hs, enc_W, enc_b, pre_enc, 16384, 512, 1024);

    for (int s = 0; s < NSTEPS; ++s){
        k_e<<<dim3(8, 32), 256, 0, stream>>>(pre_enc, aw, g1, conv_W, att_W,
                                             gvec_W, gvec_b, e_buf);
        k_soft_attc<<<dim3(8, 32), 256, 0, stream>>>(e_buf, hs, hlens, ys_pad,
                                                     embed_W, aw, x0, s);
        k_gates0<<<512, 256, 0, stream>>>(x0, w_ih0, w_hh0, g0);
        k_lstm0<<<128, 256, 0, stream>>>(g0, b_ih0, b_hh0, c0, x0, x1);
        k_gates1<<<576, 256, 0, stream>>>(x1, w_ih1, w_hh1, dec_W, g1);
        k_lstm1<<<128, 256, 0, stream>>>(g1, b_ih1, b_hh1, c1, x1, zs, s);
    }

    k_gemm_nt<true,true><<<dim3(33, 79), 256, 0, stream>>>(
        zs, out_W, out_b, out, 4128, 5000, 1024);
}